// Round 6
// baseline (1130.037 us; speedup 1.0000x reference)
//
#include <hip/hip_runtime.h>
#include <hip/hip_bf16.h>
#include <hip/hip_fp16.h>

#define BATCH   8192
#define HID     1024
#define HEADS   8
#define BC      2048

typedef unsigned int  u32;
typedef unsigned short u16;
typedef __attribute__((ext_vector_type(8))) short bf16x8;
typedef __attribute__((ext_vector_type(4))) float f32x4;

// ---------------------------------------------------------------------------
// hi/lo split helpers (truncation both; x = hi + lo + O(2^-16 |x|))
// ---------------------------------------------------------------------------
__device__ __forceinline__ u32 pack_hi2(u32 u0, u32 u1) {
    return (u0 >> 16) | (u1 & 0xFFFF0000u);
}
__device__ __forceinline__ void split1(float x, u16& h, u16& l) {
    const u32 u = __float_as_uint(x);
    h = (u16)(u >> 16);
    const float r = x - __uint_as_float(u & 0xFFFF0000u);
    l = (u16)(__float_as_uint(r) >> 16);
}
__device__ __forceinline__ void splitA4(float4 v, uint2& hi, uint2& lo) {
    u32 u0 = __float_as_uint(v.x), u1 = __float_as_uint(v.y),
        u2 = __float_as_uint(v.z), u3 = __float_as_uint(v.w);
    float r0 = v.x - __uint_as_float(u0 & 0xFFFF0000u);
    float r1 = v.y - __uint_as_float(u1 & 0xFFFF0000u);
    float r2 = v.z - __uint_as_float(u2 & 0xFFFF0000u);
    float r3 = v.w - __uint_as_float(u3 & 0xFFFF0000u);
    hi.x = pack_hi2(u0, u1);
    hi.y = pack_hi2(u2, u3);
    lo.x = pack_hi2(__float_as_uint(r0), __float_as_uint(r1));
    lo.y = pack_hi2(__float_as_uint(r2), __float_as_uint(r3));
}

// async global->LDS, 16 B per lane (used only by gemm_cvt B-staging)
__device__ __forceinline__ void gld16(const u16* g, u16* l) {
    __builtin_amdgcn_global_load_lds(
        (const __attribute__((address_space(1))) u32*)g,
        (__attribute__((address_space(3))) u32*)l, 16, 0, 0);
}

// ---------------------------------------------------------------------------
// Weight conversion: W fp32 [K][1024] (z-batched) -> hi/lo bf16 planes in
// k-tiled transposed layout  Wt[kt][n][32]  (kt = k/32), linear.
// ---------------------------------------------------------------------------
__global__ __launch_bounds__(256) void split_weight_kernel(
    const float* __restrict__ W, u16* __restrict__ hi, u16* __restrict__ lo,
    int K)
{
    const long long zoff = (long long)blockIdx.z * K * 1024;
    const int kt  = blockIdx.x;
    const int n0  = blockIdx.y * 128;
    const int tid = threadIdx.x;
    const int k   = tid >> 3;            // 0..31
    const int ng  = (tid & 7) * 16;      // 0,16,...,112
    const float* src = W + zoff + (long long)(kt * 32 + k) * 1024 + n0 + ng;
    u16* dh = hi + zoff + ((long long)kt * 1024 + n0) * 32 + k;
    u16* dl = lo + zoff + ((long long)kt * 1024 + n0) * 32 + k;
#pragma unroll
    for (int t = 0; t < 4; t++) {
        const float4 v = *(const float4*)(src + t * 4);
        u16 h0, l0, h1, l1, h2, l2, h3, l3;
        split1(v.x, h0, l0); split1(v.y, h1, l1);
        split1(v.z, h2, l2); split1(v.w, h3, l3);
        const int nb = (ng + t * 4) * 32;
        dh[nb]      = h0; dl[nb]      = l0;
        dh[nb + 32] = h1; dl[nb + 32] = l1;
        dh[nb + 64] = h2; dl[nb + 64] = l2;
        dh[nb + 96] = h3; dl[nb + 96] = l3;
    }
}

// ---------------------------------------------------------------------------
// Direct-fragment GEMM machinery: fragments loaded global->VGPR (1 KB
// coalesced dwordx4 per (i,plane)), no LDS, no K-loop barrier.
// Dual fragment sets give an unroll-2 software pipeline: while MFMAs of one
// set run, the other set's 16 loads are in flight (partial vmcnt waits).
// ---------------------------------------------------------------------------
struct Frags {
    bf16x8 ah[4], al[4], bh[4], bl[4];
};

__device__ __forceinline__ void load_set(
    Frags& f,
    const u16* __restrict__ Ahp, const u16* __restrict__ Alp,
    const u16* __restrict__ Bhp, const u16* __restrict__ Blp,
    long long abase, long long bbase)
{
#pragma unroll
    for (int i = 0; i < 4; i++) {
        f.ah[i] = *(const bf16x8*)(Ahp + abase + i * 512);
        f.al[i] = *(const bf16x8*)(Alp + abase + i * 512);
        f.bh[i] = *(const bf16x8*)(Bhp + bbase + i * 512);
        f.bl[i] = *(const bf16x8*)(Blp + bbase + i * 512);
    }
}

__device__ __forceinline__ void mfma_set(f32x4 acc[4][4], const Frags& f)
{
#pragma unroll
    for (int i = 0; i < 4; i++)
#pragma unroll
        for (int j = 0; j < 4; j++) {
            acc[i][j] = __builtin_amdgcn_mfma_f32_16x16x32_bf16(f.ah[i], f.bh[j], acc[i][j], 0, 0, 0);
            acc[i][j] = __builtin_amdgcn_mfma_f32_16x16x32_bf16(f.ah[i], f.bl[j], acc[i][j], 0, 0, 0);
            acc[i][j] = __builtin_amdgcn_mfma_f32_16x16x32_bf16(f.al[i], f.bh[j], acc[i][j], 0, 0, 0);
        }
}

#define DIRECT_GEOM \
    const int tid  = threadIdx.x; \
    const int lane = tid & 63; \
    const int wv   = tid >> 6; \
    const int wm   = wv >> 1, wn = wv & 1; \
    const int fr   = lane & 15; \
    const int fq   = lane >> 4; \
    const int m0   = blockIdx.y * 128; \
    const int n0   = blockIdx.x * 128;

// ===========================================================================
// GEMM (fast path): A,B from pre-split planes; direct-fragment, barrier-free.
// OUTP=1: write hi/lo planes (A-tiled, stride MC, row offset moff).
// OUTP=0: write fp32 row-major [*, 1024].   K must be a multiple of 64.
// ===========================================================================
template <int RELU, int OUTP>
__global__ __launch_bounds__(256) void gemm_fast(
    const u16* __restrict__ Ahp, const u16* __restrict__ Alp, int MA, int moff,
    const u16* __restrict__ Bhp, const u16* __restrict__ Blp,
    const float* __restrict__ bias,
    float* __restrict__ Cf,
    u16* __restrict__ Chp, u16* __restrict__ Clp, int MC,
    int K)
{
    DIRECT_GEOM

    f32x4 acc[4][4];
#pragma unroll
    for (int i = 0; i < 4; i++)
#pragma unroll
        for (int j = 0; j < 4; j++) acc[i][j] = 0;

    const long long astep = (long long)MA * 32;
    const long long bstep = 1024LL * 32;
    const long long a0 = ((long long)moff + m0 + wm * 64 + fr) * 32 + fq * 8;
    const long long b0 = ((long long)n0 + wn * 64 + fr) * 32 + fq * 8;

    const int KT = K >> 5;
    Frags f0, f1;
    load_set(f0, Ahp, Alp, Bhp, Blp, a0, b0);
    for (int kt = 0; kt < KT; kt += 2) {
        load_set(f1, Ahp, Alp, Bhp, Blp,
                 a0 + (kt + 1) * astep, b0 + (kt + 1) * bstep);
        mfma_set(acc, f0);
        const int k2 = (kt + 2 < KT) ? kt + 2 : 0;
        load_set(f0, Ahp, Alp, Bhp, Blp, a0 + k2 * astep, b0 + k2 * bstep);
        mfma_set(acc, f1);
    }

#pragma unroll
    for (int j = 0; j < 4; j++) {
        const int n = n0 + wn * 64 + j * 16 + fr;
        const float bb = bias[n];
#pragma unroll
        for (int i = 0; i < 4; i++) {
#pragma unroll
            for (int r = 0; r < 4; r++) {
                const int m = m0 + wm * 64 + i * 16 + fq * 4 + r;
                float v = acc[i][j][r] + bb;
                if (RELU) v = fmaxf(v, 0.0f);
                if (OUTP) {
                    u16 h, l;
                    split1(v, h, l);
                    const long long d = ((long long)(n >> 5) * MC + moff + m) * 32 + (n & 31);
                    Chp[d] = h;
                    Clp[d] = l;
                } else {
                    Cf[(long long)m * 1024 + n] = v;
                }
            }
        }
    }
}

// ===========================================================================
// GEMM (convert path, enc/dec): A fp32 (2-region concat), split in-kernel
// via LDS (r5 structure); B async from planes.  Output: hi/lo planes.
// ===========================================================================
template <int RELU>
__global__ __launch_bounds__(256) void gemm_cvt(
    const float* __restrict__ src1, int lda1, int kofs1,
    const float* __restrict__ src2, int lda2, int ksplit,
    const u16* __restrict__ Bhp, const u16* __restrict__ Blp,
    const float* __restrict__ bias,
    u16* __restrict__ Chp, u16* __restrict__ Clp, int MC,
    int K)
{
    __shared__ alignas(16) u16 Ah[4096], Al[4096], Bh[4096], Bl[4096];
    DIRECT_GEOM
    const int fqx  = (fq ^ (fr & 3)) * 8;
    const int lro  = (lane >> 2) * 32 + (((lane & 3) ^ ((lane >> 2) & 3)) * 8);
    const int br0  = wv * 16;
    const int br1  = 64 + wv * 16;
    const int ar   = tid >> 3;           // 0..31
    const int akq  = tid & 7;            // float4 group 0..7
    const int awoff = (((akq >> 1) ^ (ar & 3)) * 8) + (akq & 1) * 4;

    f32x4 acc[4][4];
#pragma unroll
    for (int i = 0; i < 4; i++)
#pragma unroll
        for (int j = 0; j < 4; j++) acc[i][j] = 0;

    const int KT = K >> 5;
    for (int kt = 0; kt < KT; kt++) {
        const int k0 = kt * 32;
        const float* srcp; int ldk, kc;
        if (k0 < ksplit) { srcp = src1; ldk = lda1; kc = k0 + kofs1; }
        else             { srcp = src2; ldk = lda2; kc = k0 - ksplit; }

        const u16* Bg  = Bhp + ((long long)kt * 1024 + n0) * 32;
        const u16* Bg2 = Blp + ((long long)kt * 1024 + n0) * 32;
        gld16(Bg  + br0 * 32 + lro, &Bh[br0 * 32]);
        gld16(Bg  + br1 * 32 + lro, &Bh[br1 * 32]);
        gld16(Bg2 + br0 * 32 + lro, &Bl[br0 * 32]);
        gld16(Bg2 + br1 * 32 + lro, &Bl[br1 * 32]);

#pragma unroll
        for (int it = 0; it < 4; it++) {
            const int row = ar + it * 32;
            const float4 v = *(const float4*)(srcp + (long long)(m0 + row) * ldk + kc + akq * 4);
            uint2 hi, lo;
            splitA4(v, hi, lo);
            *(uint2*)&Ah[row * 32 + awoff] = hi;
            *(uint2*)&Al[row * 32 + awoff] = lo;
        }
        __syncthreads();

        bf16x8 ah[4], al[4], bh[4], bl[4];
#pragma unroll
        for (int i = 0; i < 4; i++) {
            const int off = (wm * 64 + i * 16 + fr) * 32 + fqx;
            ah[i] = *(const bf16x8*)&Ah[off];
            al[i] = *(const bf16x8*)&Al[off];
        }
#pragma unroll
        for (int j = 0; j < 4; j++) {
            const int off = (wn * 64 + j * 16 + fr) * 32 + fqx;
            bh[j] = *(const bf16x8*)&Bh[off];
            bl[j] = *(const bf16x8*)&Bl[off];
        }
#pragma unroll
        for (int i = 0; i < 4; i++)
#pragma unroll
            for (int j = 0; j < 4; j++) {
                acc[i][j] = __builtin_amdgcn_mfma_f32_16x16x32_bf16(ah[i], bh[j], acc[i][j], 0, 0, 0);
                acc[i][j] = __builtin_amdgcn_mfma_f32_16x16x32_bf16(ah[i], bl[j], acc[i][j], 0, 0, 0);
                acc[i][j] = __builtin_amdgcn_mfma_f32_16x16x32_bf16(al[i], bh[j], acc[i][j], 0, 0, 0);
            }
        __syncthreads();
    }

#pragma unroll
    for (int j = 0; j < 4; j++) {
        const int n = n0 + wn * 64 + j * 16 + fr;
        const float bb = bias[n];
#pragma unroll
        for (int i = 0; i < 4; i++) {
#pragma unroll
            for (int r = 0; r < 4; r++) {
                const int m = m0 + wm * 64 + i * 16 + fq * 4 + r;
                float v = acc[i][j][r] + bb;
                if (RELU) v = fmaxf(v, 0.0f);
                u16 h, l;
                split1(v, h, l);
                const long long d = ((long long)(n >> 5) * MC + m) * 32 + (n & 31);
                Chp[d] = h;
                Clp[d] = l;
            }
        }
    }
}

// ===========================================================================
// Heads: per-head direct-fragment GEMM (barrier-free K-loop); epilogue
// writes relu(head) fp16 + partial score dots vs decH.  Grid (8, BC/128, 8).
// ===========================================================================
__global__ __launch_bounds__(256) void heads_kernel(
    const u16* __restrict__ Ahp, const u16* __restrict__ Alp, int MA, int moff,
    const u16* __restrict__ Whp, const u16* __restrict__ Wlp,
    const float* __restrict__ b_heads,
    const float* __restrict__ decH,      // chunk-local [BC][1024]
    __half* __restrict__ headsb,         // [BC][8][1024]
    float* __restrict__ scoresp)         // [64][BC]
{
    __shared__ float scred[2][128];
    DIRECT_GEOM
    const int h = blockIdx.z;
    const u16* Bhp = Whp + (long long)h * 1024 * 1024;
    const u16* Blp = Wlp + (long long)h * 1024 * 1024;
    const float* bias = b_heads + h * 1024;

    f32x4 acc[4][4];
#pragma unroll
    for (int i = 0; i < 4; i++)
#pragma unroll
        for (int j = 0; j < 4; j++) acc[i][j] = 0;

    const long long astep = (long long)MA * 32;
    const long long bstep = 1024LL * 32;
    const long long a0 = ((long long)moff + m0 + wm * 64 + fr) * 32 + fq * 8;
    const long long b0 = ((long long)n0 + wn * 64 + fr) * 32 + fq * 8;

    Frags f0, f1;
    load_set(f0, Ahp, Alp, Bhp, Blp, a0, b0);
    for (int kt = 0; kt < 32; kt += 2) {
        load_set(f1, Ahp, Alp, Bhp, Blp,
                 a0 + (kt + 1) * astep, b0 + (kt + 1) * bstep);
        mfma_set(acc, f0);
        const int k2 = (kt + 2 < 32) ? kt + 2 : 0;
        load_set(f0, Ahp, Alp, Bhp, Blp, a0 + k2 * astep, b0 + k2 * bstep);
        mfma_set(acc, f1);
    }

    // epilogue: relu -> fp16 headsb, partial score vs decH
    float part[4][4];
#pragma unroll
    for (int i = 0; i < 4; i++)
#pragma unroll
        for (int r = 0; r < 4; r++) part[i][r] = 0.0f;

#pragma unroll
    for (int j = 0; j < 4; j++) {
        const int n = n0 + wn * 64 + j * 16 + fr;
        const float bb = bias[n];
#pragma unroll
        for (int i = 0; i < 4; i++) {
#pragma unroll
            for (int r = 0; r < 4; r++) {
                const int b_loc = m0 + wm * 64 + i * 16 + fq * 4 + r;
                const float v = fmaxf(acc[i][j][r] + bb, 0.0f);
                headsb[((long long)b_loc * HEADS + h) * 1024 + n] = __float2half(v);
                part[i][r] = fmaf(v, decH[(long long)b_loc * 1024 + n], part[i][r]);
            }
        }
    }
#pragma unroll
    for (int off = 1; off < 16; off <<= 1)
#pragma unroll
        for (int i = 0; i < 4; i++)
#pragma unroll
            for (int r = 0; r < 4; r++)
                part[i][r] += __shfl_xor(part[i][r], off, 64);

    if (fr == 0) {
#pragma unroll
        for (int i = 0; i < 4; i++)
#pragma unroll
            for (int r = 0; r < 4; r++)
                scred[wn][wm * 64 + i * 16 + fq * 4 + r] = part[i][r];
    }
    __syncthreads();
    if (tid < 128) {
        const float sv = scred[0][tid] + scred[1][tid];
        scoresp[(long long)(h * 8 + blockIdx.x) * BC + m0 + tid] = sv;
    }
}

// ---------------------------------------------------------------------------
// softmax over heads (per chunk)
// ---------------------------------------------------------------------------
__global__ __launch_bounds__(256) void softmax_kernel(
    const float* __restrict__ scoresp, float* __restrict__ attn)
{
    const int b = blockIdx.x * 256 + threadIdx.x;   // 0..BC-1
    float sc[HEADS];
#pragma unroll
    for (int h = 0; h < HEADS; h++) {
        float s = 0.0f;
#pragma unroll
        for (int nt = 0; nt < 8; nt++)
            s += scoresp[(long long)(h * 8 + nt) * BC + b];
        sc[h] = s;
    }
    float mx = sc[0];
#pragma unroll
    for (int h = 1; h < HEADS; h++) mx = fmaxf(mx, sc[h]);
    float e[HEADS], sum = 0.0f;
#pragma unroll
    for (int h = 0; h < HEADS; h++) { e[h] = __expf(sc[h] - mx); sum += e[h]; }
    const float inv = 1.0f / sum;
#pragma unroll
    for (int h = 0; h < HEADS; h++) attn[(long long)b * HEADS + h] = e[h] * inv;
}

// ---------------------------------------------------------------------------
// context: ctx[b][d] = sum_h attn[b][h]*heads[b][h][d]; writes hi/lo planes
// ---------------------------------------------------------------------------
__global__ __launch_bounds__(256) void context_kernel(
    const __half* __restrict__ headsb, const float* __restrict__ attn,
    u16* __restrict__ ctx_hi, u16* __restrict__ ctx_lo, int MC, int row0)
{
    const int b = blockIdx.x;
    const int d = threadIdx.x * 4;
    float w[HEADS];
#pragma unroll
    for (int h = 0; h < HEADS; h++) w[h] = attn[(long long)b * HEADS + h];
    float4 acc = make_float4(0.f, 0.f, 0.f, 0.f);
#pragma unroll
    for (int h = 0; h < HEADS; h++) {
        const __half2* hp = (const __half2*)(headsb + ((long long)b * HEADS + h) * 1024 + d);
        const float2 f0 = __half22float2(hp[0]);
        const float2 f1 = __half22float2(hp[1]);
        acc.x = fmaf(w[h], f0.x, acc.x);
        acc.y = fmaf(w[h], f0.y, acc.y);
        acc.z = fmaf(w[h], f1.x, acc.z);
        acc.w = fmaf(w[h], f1.y, acc.w);
    }
    uint2 hi, lo;
    splitA4(acc, hi, lo);
    const long long off = ((long long)(d >> 5) * MC + row0 + b) * 32 + (d & 31);
    *(uint2*)(ctx_hi + off) = hi;
    *(uint2*)(ctx_lo + off) = lo;
}

// ---------------------------------------------------------------------------
// fc2: q[b] = sum_d x[b,d]*W2[d] + b2[0]
// ---------------------------------------------------------------------------
__global__ __launch_bounds__(256) void fc2_kernel(
    const float* __restrict__ x, const float* __restrict__ W2,
    const float* __restrict__ b2, float* __restrict__ q)
{
    const int b   = blockIdx.x;
    const int tid = threadIdx.x;
    __shared__ float red[4];

    const float4 xv = *(const float4*)(x + (long long)b * 1024 + tid * 4);
    const float4 wv = *(const float4*)(W2 + tid * 4);
    float p = xv.x * wv.x + xv.y * wv.y + xv.z * wv.z + xv.w * wv.w;
#pragma unroll
    for (int off = 32; off > 0; off >>= 1) p += __shfl_down(p, off, 64);
    if ((tid & 63) == 0) red[tid >> 6] = p;
    __syncthreads();
    if (tid == 0) q[b] = red[0] + red[1] + red[2] + red[3] + b2[0];
}

// ---------------------------------------------------------------------------
extern "C" void kernel_launch(void* const* d_in, const int* in_sizes, int n_in,
                              void* d_out, int out_size, void* d_ws, size_t ws_size,
                              hipStream_t stream)
{
    const float* s        = (const float*)d_in[0];
    const float* a        = (const float*)d_in[1];
    const float* W_enc_in = (const float*)d_in[2];
    const float* b_enc_in = (const float*)d_in[3];
    const float* W_dec_in = (const float*)d_in[4];
    const float* b_dec_in = (const float*)d_in[5];
    const float* W_eh     = (const float*)d_in[6];
    const float* b_eh     = (const float*)d_in[7];
    const float* W_heads  = (const float*)d_in[8];
    const float* b_heads  = (const float*)d_in[9];
    const float* W_dh     = (const float*)d_in[10];
    const float* b_dh     = (const float*)d_in[11];
    const float* W1       = (const float*)d_in[12];
    const float* b1       = (const float*)d_in[13];
    const float* W2       = (const float*)d_in[14];
    const float* b2       = (const float*)d_in[15];
    float* q_out = (float*)d_out;

    // ---- weight plane layout (shorts) -------------------------------------
    u16* P = (u16*)d_ws;
    u16* enc_hi = P; P += 557056;      // 544*1024
    u16* enc_lo = P; P += 557056;
    u16* dec_hi = P; P += 98304;       // 96*1024
    u16* dec_lo = P; P += 98304;
    u16* eh_hi  = P; P += 1048576;
    u16* eh_lo  = P; P += 1048576;
    u16* dh_hi  = P; P += 1048576;
    u16* dh_lo  = P; P += 1048576;
    u16* w1_hi  = P; P += 1048576;
    u16* w1_lo  = P; P += 1048576;
    u16* wh_hi  = P; P += 8388608;     // 8*1024*1024
    u16* wh_lo  = P; P += 8388608;
    char* act = (char*)P;              // 48,758,784 bytes consumed

    const dim3 blk(256);

    // ---- weight conversions ------------------------------------------------
    split_weight_kernel<<<dim3(17, 8, 1), blk, 0, stream>>>(W_enc_in, enc_hi, enc_lo, 544);
    split_weight_kernel<<<dim3(3, 8, 1), blk, 0, stream>>>(W_dec_in, dec_hi, dec_lo, 96);
    split_weight_kernel<<<dim3(32, 8, 1), blk, 0, stream>>>(W_eh, eh_hi, eh_lo, 1024);
    split_weight_kernel<<<dim3(32, 8, 1), blk, 0, stream>>>(W_dh, dh_hi, dh_lo, 1024);
    split_weight_kernel<<<dim3(32, 8, 1), blk, 0, stream>>>(W1, w1_hi, w1_lo, 1024);
    split_weight_kernel<<<dim3(32, 8, 8), blk, 0, stream>>>(W_heads, wh_hi, wh_lo, 1024);

    const bool high = (ws_size >= 150011904ULL);

    if (high) {
        u16*    bufA_hi = (u16*)act;
        u16*    bufA_lo = bufA_hi + 8388608;
        __half* headsb  = (__half*)act;
        u16*    encH_hi = (u16*)(act + 33554432);
        u16*    encH_lo = encH_hi + 8388608;
        float*  decH    = (float*)(act + 2LL * 33554432);
        float*  scoresp = (float*)(act + 3LL * 33554432);
        float*  attnb   = scoresp + 64LL * BC;

        const dim3 gg(8, 64, 1);
        gemm_cvt<0><<<gg, blk, 0, stream>>>(s, 512, 0, a, 128, 512,
            enc_hi, enc_lo, b_enc_in, bufA_hi, bufA_lo, 8192, 544);
        gemm_fast<1, 1><<<gg, blk, 0, stream>>>(bufA_hi, bufA_lo, 8192, 0,
            eh_hi, eh_lo, b_eh, nullptr, encH_hi, encH_lo, 8192, 1024);
        gemm_cvt<0><<<gg, blk, 0, stream>>>(a, 128, 32, a, 128, 1 << 28,
            dec_hi, dec_lo, b_dec_in, bufA_hi, bufA_lo, 8192, 96);
        gemm_fast<1, 0><<<gg, blk, 0, stream>>>(bufA_hi, bufA_lo, 8192, 0,
            dh_hi, dh_lo, b_dh, decH, nullptr, nullptr, 0, 1024);

        for (int c = 0; c < BATCH / BC; c++) {
            heads_kernel<<<dim3(8, BC / 128, 8), blk, 0, stream>>>(
                encH_hi, encH_lo, 8192, c * BC, wh_hi, wh_lo, b_heads,
                decH + (long long)c * BC * 1024, headsb, scoresp);
            softmax_kernel<<<dim3(BC / 256), blk, 0, stream>>>(scoresp, attnb);
            context_kernel<<<dim3(BC), blk, 0, stream>>>(
                headsb, attnb, encH_hi, encH_lo, 8192, c * BC);
        }
        gemm_fast<1, 0><<<gg, blk, 0, stream>>>(encH_hi, encH_lo, 8192, 0,
            w1_hi, w1_lo, b1, decH, nullptr, nullptr, 0, 1024);
        fc2_kernel<<<dim3(BATCH), blk, 0, stream>>>(decH, W2, b2, q_out);
    } else {
        __half* headsb  = (__half*)act;
        u16*    bufA_hi = (u16*)act;
        u16*    bufA_lo = bufA_hi + 2097152;
        u16*    encH_hi = (u16*)(act + 33554432);
        u16*    encH_lo = encH_hi + 2097152;
        float*  decH    = (float*)(act + 33554432 + 8388608);
        float*  scoresp = (float*)(act + 33554432 + 2LL * 8388608);
        float*  attnb   = scoresp + 64LL * BC;

        const dim3 gg(8, BC / 128, 1);
        for (int c = 0; c < BATCH / BC; c++) {
            const float* sC = s + (long long)c * BC * 512;
            const float* aC = a + (long long)c * BC * 128;
            gemm_cvt<0><<<gg, blk, 0, stream>>>(sC, 512, 0, aC, 128, 512,
                enc_hi, enc_lo, b_enc_in, bufA_hi, bufA_lo, BC, 544);
            gemm_fast<1, 1><<<gg, blk, 0, stream>>>(bufA_hi, bufA_lo, BC, 0,
                eh_hi, eh_lo, b_eh, nullptr, encH_hi, encH_lo, BC, 1024);
            gemm_cvt<0><<<gg, blk, 0, stream>>>(aC, 128, 32, aC, 128, 1 << 28,
                dec_hi, dec_lo, b_dec_in, bufA_hi, bufA_lo, BC, 96);
            gemm_fast<1, 0><<<gg, blk, 0, stream>>>(bufA_hi, bufA_lo, BC, 0,
                dh_hi, dh_lo, b_dh, decH, nullptr, nullptr, 0, 1024);
            heads_kernel<<<dim3(8, BC / 128, 8), blk, 0, stream>>>(
                encH_hi, encH_lo, BC, 0, wh_hi, wh_lo, b_heads,
                decH, headsb, scoresp);
            softmax_kernel<<<dim3(BC / 256), blk, 0, stream>>>(scoresp, attnb);
            context_kernel<<<dim3(BC), blk, 0, stream>>>(
                headsb, attnb, encH_hi, encH_lo, BC, 0);
            gemm_fast<1, 0><<<gg, blk, 0, stream>>>(encH_hi, encH_lo, BC, 0,
                w1_hi, w1_lo, b1, decH, nullptr, nullptr, 0, 1024);
            fc2_kernel<<<dim3(BC), blk, 0, stream>>>(decH, W2, b2, q_out + (long long)c * BC);
        }
    }
}

// Round 7
// 840.898 us; speedup vs baseline: 1.3438x; 1.3438x over previous
//
#include <hip/hip_runtime.h>
#include <hip/hip_bf16.h>
#include <hip/hip_fp16.h>

#define BATCH   8192
#define HID     1024
#define HEADS   8
#define BC      2048

typedef unsigned int  u32;
typedef unsigned short u16;
typedef __attribute__((ext_vector_type(8))) short bf16x8;
typedef __attribute__((ext_vector_type(4))) float f32x4;
typedef __attribute__((ext_vector_type(16))) float f32x16;

// ---------------------------------------------------------------------------
// hi/lo split helpers (truncation both; x = hi + lo + O(2^-16 |x|))
// ---------------------------------------------------------------------------
__device__ __forceinline__ u32 pack_hi2(u32 u0, u32 u1) {
    return (u0 >> 16) | (u1 & 0xFFFF0000u);
}
__device__ __forceinline__ void split1(float x, u16& h, u16& l) {
    const u32 u = __float_as_uint(x);
    h = (u16)(u >> 16);
    const float r = x - __uint_as_float(u & 0xFFFF0000u);
    l = (u16)(__float_as_uint(r) >> 16);
}
__device__ __forceinline__ void splitA4(float4 v, uint2& hi, uint2& lo) {
    u32 u0 = __float_as_uint(v.x), u1 = __float_as_uint(v.y),
        u2 = __float_as_uint(v.z), u3 = __float_as_uint(v.w);
    float r0 = v.x - __uint_as_float(u0 & 0xFFFF0000u);
    float r1 = v.y - __uint_as_float(u1 & 0xFFFF0000u);
    float r2 = v.z - __uint_as_float(u2 & 0xFFFF0000u);
    float r3 = v.w - __uint_as_float(u3 & 0xFFFF0000u);
    hi.x = pack_hi2(u0, u1);
    hi.y = pack_hi2(u2, u3);
    lo.x = pack_hi2(__float_as_uint(r0), __float_as_uint(r1));
    lo.y = pack_hi2(__float_as_uint(r2), __float_as_uint(r3));
}

// async global->LDS, 16 B per lane; lds base must be wave-uniform
__device__ __forceinline__ void gld16(const u16* g, u16* l) {
    __builtin_amdgcn_global_load_lds(
        (const __attribute__((address_space(1))) u32*)g,
        (__attribute__((address_space(3))) u32*)l, 16, 0, 0);
}

// ---------------------------------------------------------------------------
// Combined weight conversion (ONE launch): 13 z-slices ->
//  z=0 eh, z=1 dh, z=2 w1, z=3..10 heads h, z=11 enc, z=12 dec
// W fp32 [K][1024] -> hi/lo planes, k-tiled transposed  Wt[kt][n][32].
// ---------------------------------------------------------------------------
struct WSplitArgs {
    const float* src[6];
    u16* hi[6];
    u16* lo[6];
};

__global__ __launch_bounds__(256) void split_weight_all(WSplitArgs args)
{
    const int z = blockIdx.z;
    int which, zz = 0;
    if (z < 3)       { which = z; }
    else if (z < 11) { which = 3; zz = z - 3; }
    else             { which = z - 7; }          // 4 = enc, 5 = dec
    const int KT = (which == 4) ? 17 : (which == 5 ? 3 : 32);
    const int kt = blockIdx.x;
    if (kt >= KT) return;
    const int K = KT * 32;
    const long long zoff = (long long)zz * K * 1024;
    const float* W  = args.src[which] + zoff;
    u16* hi = args.hi[which] + zoff;
    u16* lo = args.lo[which] + zoff;

    const int n0  = blockIdx.y * 128;
    const int tid = threadIdx.x;
    const int k   = tid >> 3;            // 0..31
    const int ng  = (tid & 7) * 16;      // 0,16,...,112
    const float* src = W + (long long)(kt * 32 + k) * 1024 + n0 + ng;
    u16* dh = hi + ((long long)kt * 1024 + n0) * 32 + k;
    u16* dl = lo + ((long long)kt * 1024 + n0) * 32 + k;
#pragma unroll
    for (int t = 0; t < 4; t++) {
        const float4 v = *(const float4*)(src + t * 4);
        u16 h0, l0, h1, l1, h2, l2, h3, l3;
        split1(v.x, h0, l0); split1(v.y, h1, l1);
        split1(v.z, h2, l2); split1(v.w, h3, l3);
        const int nb = (ng + t * 4) * 32;
        dh[nb]      = h0; dl[nb]      = l0;
        dh[nb + 32] = h1; dl[nb + 32] = l1;
        dh[nb + 64] = h2; dl[nb + 64] = l2;
        dh[nb + 96] = h3; dl[nb + 96] = l3;
    }
}

// Common geometry for the 32x32x16 MFMA kernels.
// Plane layout per kt: rows [0..127] x 32 shorts, logical k-group g (k>>3)
// stored at physical slot g^(row&3)  (matches gld16's lro source swizzle).
#define MFMA32_GEOM \
    const int tid  = threadIdx.x; \
    const int lane = tid & 63; \
    const int wv   = tid >> 6; \
    const int wm   = wv >> 1, wn = wv & 1; \
    const int c    = lane & 31; \
    const int hh   = lane >> 5; \
    const int cs   = c & 3; \
    const int m0   = blockIdx.y * 128; \
    const int n0   = blockIdx.x * 128; \
    const int lro  = (lane >> 2) * 32 + (((lane & 3) ^ ((lane >> 2) & 3)) * 8); \
    const int br0  = wv * 16; \
    const int br1  = 64 + wv * 16;

#define STAGE8(Ahp_, Alp_, Bhp_, Blp_, aoff_, boff_) \
    { \
        const u16* Ag_  = (Ahp_) + (aoff_); \
        const u16* Ag2_ = (Alp_) + (aoff_); \
        const u16* Bg_  = (Bhp_) + (boff_); \
        const u16* Bg2_ = (Blp_) + (boff_); \
        gld16(Ag_  + br0 * 32 + lro, &Ah[br0 * 32]); \
        gld16(Ag_  + br1 * 32 + lro, &Ah[br1 * 32]); \
        gld16(Ag2_ + br0 * 32 + lro, &Al[br0 * 32]); \
        gld16(Ag2_ + br1 * 32 + lro, &Al[br1 * 32]); \
        gld16(Bg_  + br0 * 32 + lro, &Bh[br0 * 32]); \
        gld16(Bg_  + br1 * 32 + lro, &Bh[br1 * 32]); \
        gld16(Bg2_ + br0 * 32 + lro, &Bl[br0 * 32]); \
        gld16(Bg2_ + br1 * 32 + lro, &Bl[br1 * 32]); \
    }

// 2 k-steps of 32x32x16 MFMAs (24 instrs) over the staged BK=32 slab
#define MFMA32_SLAB(accv) \
    _Pragma("unroll") \
    for (int s = 0; s < 2; s++) { \
        bf16x8 av0[2], av1[2], bv0[2], bv1[2]; \
        const int ko = ((s * 2 + hh) ^ cs) * 8; \
        _Pragma("unroll") \
        for (int t = 0; t < 2; t++) { \
            const int ao = (wm * 64 + t * 32 + c) * 32 + ko; \
            const int bo = (wn * 64 + t * 32 + c) * 32 + ko; \
            av0[t] = *(const bf16x8*)&Ah[ao]; \
            av1[t] = *(const bf16x8*)&Al[ao]; \
            bv0[t] = *(const bf16x8*)&Bh[bo]; \
            bv1[t] = *(const bf16x8*)&Bl[bo]; \
        } \
        _Pragma("unroll") \
        for (int i = 0; i < 2; i++) \
            _Pragma("unroll") \
            for (int j = 0; j < 2; j++) { \
                accv[i][j] = __builtin_amdgcn_mfma_f32_32x32x16_bf16(av0[i], bv0[j], accv[i][j], 0, 0, 0); \
                accv[i][j] = __builtin_amdgcn_mfma_f32_32x32x16_bf16(av0[i], bv1[j], accv[i][j], 0, 0, 0); \
                accv[i][j] = __builtin_amdgcn_mfma_f32_32x32x16_bf16(av1[i], bv0[j], accv[i][j], 0, 0, 0); \
            } \
    }

// ===========================================================================
// GEMM (fast path): A,B from pre-split planes; async LDS staging; 32x32x16.
// OUTP=1: write hi/lo planes.  OUTP=0: fp32 row-major [*, 1024].
// ===========================================================================
template <int RELU, int OUTP>
__global__ __launch_bounds__(256) void gemm_fast(
    const u16* __restrict__ Ahp, const u16* __restrict__ Alp, int MA, int moff,
    const u16* __restrict__ Bhp, const u16* __restrict__ Blp,
    const float* __restrict__ bias,
    float* __restrict__ Cf,
    u16* __restrict__ Chp, u16* __restrict__ Clp, int MC,
    int K)
{
    __shared__ alignas(16) u16 Ah[4096], Al[4096], Bh[4096], Bl[4096];
    MFMA32_GEOM

    f32x16 acc[2][2];
    acc[0][0] = 0; acc[0][1] = 0; acc[1][0] = 0; acc[1][1] = 0;

    const int KT = K >> 5;
    for (int kt = 0; kt < KT; kt++) {
        STAGE8(Ahp, Alp, Bhp, Blp,
               ((long long)kt * MA + moff + m0) * 32,
               ((long long)kt * 1024 + n0) * 32);
        __syncthreads();
        MFMA32_SLAB(acc);
        __syncthreads();
    }

#pragma unroll
    for (int j = 0; j < 2; j++) {
        const int n = n0 + wn * 64 + j * 32 + c;
        const float bb = bias[n];
#pragma unroll
        for (int i = 0; i < 2; i++) {
#pragma unroll
            for (int reg = 0; reg < 16; reg++) {
                const int m = m0 + wm * 64 + i * 32 + 4 * hh + (reg & 3) + 8 * (reg >> 2);
                float v = acc[i][j][reg] + bb;
                if (RELU) v = fmaxf(v, 0.0f);
                if (OUTP) {
                    u16 h, l;
                    split1(v, h, l);
                    const long long d = ((long long)(n >> 5) * MC + moff + m) * 32 + (n & 31);
                    Chp[d] = h;
                    Clp[d] = l;
                } else {
                    Cf[(long long)m * 1024 + n] = v;
                }
            }
        }
    }
}

// ===========================================================================
// GEMM (convert path, enc/dec): A fp32 (2-region concat), split in-kernel
// via LDS (r5 16x16x32 structure); B async from planes.  Output: planes.
// ===========================================================================
template <int RELU>
__global__ __launch_bounds__(256) void gemm_cvt(
    const float* __restrict__ src1, int lda1, int kofs1,
    const float* __restrict__ src2, int lda2, int ksplit,
    const u16* __restrict__ Bhp, const u16* __restrict__ Blp,
    const float* __restrict__ bias,
    u16* __restrict__ Chp, u16* __restrict__ Clp, int MC,
    int K)
{
    __shared__ alignas(16) u16 Ah[4096], Al[4096], Bh[4096], Bl[4096];
    const int tid  = threadIdx.x;
    const int lane = tid & 63;
    const int wv   = tid >> 6;
    const int wm   = wv >> 1, wn = wv & 1;
    const int fr   = lane & 15;
    const int fq   = lane >> 4;
    const int m0   = blockIdx.y * 128;
    const int n0   = blockIdx.x * 128;
    const int fqx  = (fq ^ (fr & 3)) * 8;
    const int lro  = (lane >> 2) * 32 + (((lane & 3) ^ ((lane >> 2) & 3)) * 8);
    const int br0  = wv * 16;
    const int br1  = 64 + wv * 16;
    const int ar   = tid >> 3;           // 0..31
    const int akq  = tid & 7;            // float4 group 0..7
    const int awoff = (((akq >> 1) ^ (ar & 3)) * 8) + (akq & 1) * 4;

    f32x4 acc[4][4];
#pragma unroll
    for (int i = 0; i < 4; i++)
#pragma unroll
        for (int j = 0; j < 4; j++) acc[i][j] = 0;

    const int KT = K >> 5;
    for (int kt = 0; kt < KT; kt++) {
        const int k0 = kt * 32;
        const float* srcp; int ldk, kc;
        if (k0 < ksplit) { srcp = src1; ldk = lda1; kc = k0 + kofs1; }
        else             { srcp = src2; ldk = lda2; kc = k0 - ksplit; }

        const u16* Bg  = Bhp + ((long long)kt * 1024 + n0) * 32;
        const u16* Bg2 = Blp + ((long long)kt * 1024 + n0) * 32;
        gld16(Bg  + br0 * 32 + lro, &Bh[br0 * 32]);
        gld16(Bg  + br1 * 32 + lro, &Bh[br1 * 32]);
        gld16(Bg2 + br0 * 32 + lro, &Bl[br0 * 32]);
        gld16(Bg2 + br1 * 32 + lro, &Bl[br1 * 32]);

#pragma unroll
        for (int it = 0; it < 4; it++) {
            const int row = ar + it * 32;
            const float4 v = *(const float4*)(srcp + (long long)(m0 + row) * ldk + kc + akq * 4);
            uint2 hi, lo;
            splitA4(v, hi, lo);
            *(uint2*)&Ah[row * 32 + awoff] = hi;
            *(uint2*)&Al[row * 32 + awoff] = lo;
        }
        __syncthreads();

        bf16x8 ah[4], al[4], bh[4], bl[4];
#pragma unroll
        for (int i = 0; i < 4; i++) {
            const int off = (wm * 64 + i * 16 + fr) * 32 + fqx;
            ah[i] = *(const bf16x8*)&Ah[off];
            al[i] = *(const bf16x8*)&Al[off];
        }
#pragma unroll
        for (int j = 0; j < 4; j++) {
            const int off = (wn * 64 + j * 16 + fr) * 32 + fqx;
            bh[j] = *(const bf16x8*)&Bh[off];
            bl[j] = *(const bf16x8*)&Bl[off];
        }
#pragma unroll
        for (int i = 0; i < 4; i++)
#pragma unroll
            for (int j = 0; j < 4; j++) {
                acc[i][j] = __builtin_amdgcn_mfma_f32_16x16x32_bf16(ah[i], bh[j], acc[i][j], 0, 0, 0);
                acc[i][j] = __builtin_amdgcn_mfma_f32_16x16x32_bf16(ah[i], bl[j], acc[i][j], 0, 0, 0);
                acc[i][j] = __builtin_amdgcn_mfma_f32_16x16x32_bf16(al[i], bh[j], acc[i][j], 0, 0, 0);
            }
        __syncthreads();
    }

#pragma unroll
    for (int j = 0; j < 4; j++) {
        const int n = n0 + wn * 64 + j * 16 + fr;
        const float bb = bias[n];
#pragma unroll
        for (int i = 0; i < 4; i++) {
#pragma unroll
            for (int r = 0; r < 4; r++) {
                const int m = m0 + wm * 64 + i * 16 + fq * 4 + r;
                float v = acc[i][j][r] + bb;
                if (RELU) v = fmaxf(v, 0.0f);
                u16 h, l;
                split1(v, h, l);
                const long long d = ((long long)(n >> 5) * MC + m) * 32 + (n & 31);
                Chp[d] = h;
                Clp[d] = l;
            }
        }
    }
}

// ===========================================================================
// Heads: per-head 32x32x16 GEMM from planes; epilogue writes relu(head) fp16
// + partial score dots vs decH.  Grid (8, BC/128, 8).
// ===========================================================================
__global__ __launch_bounds__(256) void heads_kernel(
    const u16* __restrict__ Ahp, const u16* __restrict__ Alp, int MA, int moff,
    const u16* __restrict__ Whp, const u16* __restrict__ Wlp,
    const float* __restrict__ b_heads,
    const float* __restrict__ decH,      // chunk-local [BC][1024]
    __half* __restrict__ headsb,         // [BC][8][1024]
    float* __restrict__ scoresp)         // [64][BC]
{
    __shared__ alignas(16) u16 Ah[4096], Al[4096], Bh[4096], Bl[4096];
    __shared__ float scred[2][128];
    MFMA32_GEOM
    const int h = blockIdx.z;
    const u16* Bhp = Whp + (long long)h * 1048576;
    const u16* Blp = Wlp + (long long)h * 1048576;
    const float* bias = b_heads + h * 1024;

    f32x16 acc[2][2];
    acc[0][0] = 0; acc[0][1] = 0; acc[1][0] = 0; acc[1][1] = 0;

    for (int kt = 0; kt < 32; kt++) {
        STAGE8(Ahp, Alp, Bhp, Blp,
               ((long long)kt * MA + moff + m0) * 32,
               ((long long)kt * 1024 + n0) * 32);
        __syncthreads();
        MFMA32_SLAB(acc);
        __syncthreads();
    }

    // epilogue: relu -> fp16 headsb, partial score vs decH
    float part[2][16];
#pragma unroll
    for (int i = 0; i < 2; i++)
#pragma unroll
        for (int reg = 0; reg < 16; reg++) part[i][reg] = 0.0f;

#pragma unroll
    for (int j = 0; j < 2; j++) {
        const int n = n0 + wn * 64 + j * 32 + c;
        const float bb = bias[n];
#pragma unroll
        for (int i = 0; i < 2; i++) {
#pragma unroll
            for (int reg = 0; reg < 16; reg++) {
                const int b_loc = m0 + wm * 64 + i * 32 + 4 * hh + (reg & 3) + 8 * (reg >> 2);
                const float v = fmaxf(acc[i][j][reg] + bb, 0.0f);
                headsb[((long long)b_loc * HEADS + h) * 1024 + n] = __float2half(v);
                part[i][reg] = fmaf(v, decH[(long long)b_loc * 1024 + n], part[i][reg]);
            }
        }
    }
    // reduce across the 32 c-lanes (xor <= 16 stays within each half)
#pragma unroll
    for (int off = 1; off < 32; off <<= 1)
#pragma unroll
        for (int i = 0; i < 2; i++)
#pragma unroll
            for (int reg = 0; reg < 16; reg++)
                part[i][reg] += __shfl_xor(part[i][reg], off, 64);

    if (c == 0) {
#pragma unroll
        for (int i = 0; i < 2; i++)
#pragma unroll
            for (int reg = 0; reg < 16; reg++)
                scred[wn][wm * 64 + i * 32 + 4 * hh + (reg & 3) + 8 * (reg >> 2)] = part[i][reg];
    }
    __syncthreads();
    if (tid < 128) {
        const float sv = scred[0][tid] + scred[1][tid];
        scoresp[(long long)(h * 8 + blockIdx.x) * BC + m0 + tid] = sv;
    }
}

// ---------------------------------------------------------------------------
// context (+fused softmax): per row b, softmax over heads from scoresp,
// then ctx[b][d] = sum_h attn[h]*heads[b][h][d]; writes hi/lo planes.
// ---------------------------------------------------------------------------
__global__ __launch_bounds__(256) void context_kernel(
    const __half* __restrict__ headsb, const float* __restrict__ scoresp,
    u16* __restrict__ ctx_hi, u16* __restrict__ ctx_lo, int MC, int row0)
{
    __shared__ float sc_s[64];
    __shared__ float attn_s[HEADS];
    const int b = blockIdx.x;
    const int tid = threadIdx.x;
    if (tid < 64) sc_s[tid] = scoresp[(long long)tid * BC + b];
    __syncthreads();
    if (tid == 0) {
        float sc[HEADS];
#pragma unroll
        for (int h = 0; h < HEADS; h++) {
            float s = 0.0f;
#pragma unroll
            for (int nt = 0; nt < 8; nt++) s += sc_s[h * 8 + nt];
            sc[h] = s;
        }
        float mx = sc[0];
#pragma unroll
        for (int h = 1; h < HEADS; h++) mx = fmaxf(mx, sc[h]);
        float e[HEADS], sum = 0.0f;
#pragma unroll
        for (int h = 0; h < HEADS; h++) { e[h] = __expf(sc[h] - mx); sum += e[h]; }
        const float inv = 1.0f / sum;
#pragma unroll
        for (int h = 0; h < HEADS; h++) attn_s[h] = e[h] * inv;
    }
    __syncthreads();

    const int d = tid * 4;
    float w[HEADS];
#pragma unroll
    for (int h = 0; h < HEADS; h++) w[h] = attn_s[h];
    float4 acc = make_float4(0.f, 0.f, 0.f, 0.f);
#pragma unroll
    for (int h = 0; h < HEADS; h++) {
        const __half2* hp = (const __half2*)(headsb + ((long long)b * HEADS + h) * 1024 + d);
        const float2 f0 = __half22float2(hp[0]);
        const float2 f1 = __half22float2(hp[1]);
        acc.x = fmaf(w[h], f0.x, acc.x);
        acc.y = fmaf(w[h], f0.y, acc.y);
        acc.z = fmaf(w[h], f1.x, acc.z);
        acc.w = fmaf(w[h], f1.y, acc.w);
    }
    uint2 hi, lo;
    splitA4(acc, hi, lo);
    const long long off = ((long long)(d >> 5) * MC + row0 + b) * 32 + (d & 31);
    *(uint2*)(ctx_hi + off) = hi;
    *(uint2*)(ctx_lo + off) = lo;
}

// ---------------------------------------------------------------------------
// fc2: q[b] = sum_d x[b,d]*W2[d] + b2[0]
// ---------------------------------------------------------------------------
__global__ __launch_bounds__(256) void fc2_kernel(
    const float* __restrict__ x, const float* __restrict__ W2,
    const float* __restrict__ b2, float* __restrict__ q)
{
    const int b   = blockIdx.x;
    const int tid = threadIdx.x;
    __shared__ float red[4];

    const float4 xv = *(const float4*)(x + (long long)b * 1024 + tid * 4);
    const float4 wv = *(const float4*)(W2 + tid * 4);
    float p = xv.x * wv.x + xv.y * wv.y + xv.z * wv.z + xv.w * wv.w;
#pragma unroll
    for (int off = 32; off > 0; off >>= 1) p += __shfl_down(p, off, 64);
    if ((tid & 63) == 0) red[tid >> 6] = p;
    __syncthreads();
    if (tid == 0) q[b] = red[0] + red[1] + red[2] + red[3] + b2[0];
}

// ---------------------------------------------------------------------------
extern "C" void kernel_launch(void* const* d_in, const int* in_sizes, int n_in,
                              void* d_out, int out_size, void* d_ws, size_t ws_size,
                              hipStream_t stream)
{
    const float* s        = (const float*)d_in[0];
    const float* a        = (const float*)d_in[1];
    const float* W_enc_in = (const float*)d_in[2];
    const float* b_enc_in = (const float*)d_in[3];
    const float* W_dec_in = (const float*)d_in[4];
    const float* b_dec_in = (const float*)d_in[5];
    const float* W_eh     = (const float*)d_in[6];
    const float* b_eh     = (const float*)d_in[7];
    const float* W_heads  = (const float*)d_in[8];
    const float* b_heads  = (const float*)d_in[9];
    const float* W_dh     = (const float*)d_in[10];
    const float* b_dh     = (const float*)d_in[11];
    const float* W1       = (const float*)d_in[12];
    const float* b1       = (const float*)d_in[13];
    const float* W2       = (const float*)d_in[14];
    const float* b2       = (const float*)d_in[15];
    float* q_out = (float*)d_out;

    // ---- weight plane layout (shorts) -------------------------------------
    u16* P = (u16*)d_ws;
    u16* enc_hi = P; P += 557056;      // 544*1024
    u16* enc_lo = P; P += 557056;
    u16* dec_hi = P; P += 98304;       // 96*1024
    u16* dec_lo = P; P += 98304;
    u16* eh_hi  = P; P += 1048576;
    u16* eh_lo  = P; P += 1048576;
    u16* dh_hi  = P; P += 1048576;
    u16* dh_lo  = P; P += 1048576;
    u16* w1_hi  = P; P += 1048576;
    u16* w1_lo  = P; P += 1048576;
    u16* wh_hi  = P; P += 8388608;     // 8*1024*1024
    u16* wh_lo  = P; P += 8388608;
    char* act = (char*)P;              // 48,758,784 bytes consumed

    const dim3 blk(256);

    // ---- weight conversions: ONE launch -----------------------------------
    WSplitArgs wa;
    wa.src[0] = W_eh;    wa.hi[0] = eh_hi;  wa.lo[0] = eh_lo;
    wa.src[1] = W_dh;    wa.hi[1] = dh_hi;  wa.lo[1] = dh_lo;
    wa.src[2] = W1;      wa.hi[2] = w1_hi;  wa.lo[2] = w1_lo;
    wa.src[3] = W_heads; wa.hi[3] = wh_hi;  wa.lo[3] = wh_lo;
    wa.src[4] = W_enc_in; wa.hi[4] = enc_hi; wa.lo[4] = enc_lo;
    wa.src[5] = W_dec_in; wa.hi[5] = dec_hi; wa.lo[5] = dec_lo;
    split_weight_all<<<dim3(32, 8, 13), blk, 0, stream>>>(wa);

    const bool high = (ws_size >= 150011904ULL);

    if (high) {
        u16*    bufA_hi = (u16*)act;
        u16*    bufA_lo = bufA_hi + 8388608;
        __half* headsb  = (__half*)act;
        u16*    encH_hi = (u16*)(act + 33554432);
        u16*    encH_lo = encH_hi + 8388608;
        float*  decH    = (float*)(act + 2LL * 33554432);
        float*  scoresp = (float*)(act + 3LL * 33554432);

        const dim3 gg(8, 64, 1);
        gemm_cvt<0><<<gg, blk, 0, stream>>>(s, 512, 0, a, 128, 512,
            enc_hi, enc_lo, b_enc_in, bufA_hi, bufA_lo, 8192, 544);
        gemm_fast<1, 1><<<gg, blk, 0, stream>>>(bufA_hi, bufA_lo, 8192, 0,
            eh_hi, eh_lo, b_eh, nullptr, encH_hi, encH_lo, 8192, 1024);
        gemm_cvt<0><<<gg, blk, 0, stream>>>(a, 128, 32, a, 128, 1 << 28,
            dec_hi, dec_lo, b_dec_in, bufA_hi, bufA_lo, 8192, 96);
        gemm_fast<1, 0><<<gg, blk, 0, stream>>>(bufA_hi, bufA_lo, 8192, 0,
            dh_hi, dh_lo, b_dh, decH, nullptr, nullptr, 0, 1024);

        for (int c = 0; c < BATCH / BC; c++) {
            heads_kernel<<<dim3(8, BC / 128, 8), blk, 0, stream>>>(
                encH_hi, encH_lo, 8192, c * BC, wh_hi, wh_lo, b_heads,
                decH + (long long)c * BC * 1024, headsb, scoresp);
            context_kernel<<<dim3(BC), blk, 0, stream>>>(
                headsb, scoresp, encH_hi, encH_lo, 8192, c * BC);
        }
        gemm_fast<1, 0><<<gg, blk, 0, stream>>>(encH_hi, encH_lo, 8192, 0,
            w1_hi, w1_lo, b1, decH, nullptr, nullptr, 0, 1024);
        fc2_kernel<<<dim3(BATCH), blk, 0, stream>>>(decH, W2, b2, q_out);
    } else {
        __half* headsb  = (__half*)act;
        u16*    bufA_hi = (u16*)act;
        u16*    bufA_lo = bufA_hi + 2097152;
        u16*    encH_hi = (u16*)(act + 33554432);
        u16*    encH_lo = encH_hi + 2097152;
        float*  decH    = (float*)(act + 33554432 + 8388608);
        float*  scoresp = (float*)(act + 33554432 + 2LL * 8388608);

        const dim3 gg(8, BC / 128, 1);
        for (int c = 0; c < BATCH / BC; c++) {
            const float* sC = s + (long long)c * BC * 512;
            const float* aC = a + (long long)c * BC * 128;
            gemm_cvt<0><<<gg, blk, 0, stream>>>(sC, 512, 0, aC, 128, 512,
                enc_hi, enc_lo, b_enc_in, bufA_hi, bufA_lo, BC, 544);
            gemm_fast<1, 1><<<gg, blk, 0, stream>>>(bufA_hi, bufA_lo, BC, 0,
                eh_hi, eh_lo, b_eh, nullptr, encH_hi, encH_lo, BC, 1024);
            gemm_cvt<0><<<gg, blk, 0, stream>>>(aC, 128, 32, aC, 128, 1 << 28,
                dec_hi, dec_lo, b_dec_in, bufA_hi, bufA_lo, BC, 96);
            gemm_fast<1, 0><<<gg, blk, 0, stream>>>(bufA_hi, bufA_lo, BC, 0,
                dh_hi, dh_lo, b_dh, decH, nullptr, nullptr, 0, 1024);
            heads_kernel<<<dim3(8, BC / 128, 8), blk, 0, stream>>>(
                encH_hi, encH_lo, BC, 0, wh_hi, wh_lo, b_heads,
                decH, headsb, scoresp);
            context_kernel<<<dim3(BC), blk, 0, stream>>>(
                headsb, scoresp, encH_hi, encH_lo, BC, 0);
            gemm_fast<1, 0><<<gg, blk, 0, stream>>>(encH_hi, encH_lo, BC, 0,
                w1_hi, w1_lo, b1, decH, nullptr, nullptr, 0, 1024);
            fc2_kernel<<<dim3(BC), blk, 0, stream>>>(decH, W2, b2, q_out + (long long)c * BC);
        }
    }
}

// Round 8
// 807.314 us; speedup vs baseline: 1.3997x; 1.0416x over previous
//
#include <hip/hip_runtime.h>
#include <hip/hip_bf16.h>
#include <hip/hip_fp16.h>

#define BATCH   8192
#define HID     1024
#define HEADS   8
#define BC      2048

typedef unsigned int  u32;
typedef unsigned short u16;
typedef __attribute__((ext_vector_type(8))) short bf16x8;
typedef __attribute__((ext_vector_type(4))) float f32x4;

// ---------------------------------------------------------------------------
// hi/lo split helpers (truncation both; x = hi + lo + O(2^-16 |x|))
// ---------------------------------------------------------------------------
__device__ __forceinline__ u32 pack_hi2(u32 u0, u32 u1) {
    return (u0 >> 16) | (u1 & 0xFFFF0000u);
}
__device__ __forceinline__ void split1(float x, u16& h, u16& l) {
    const u32 u = __float_as_uint(x);
    h = (u16)(u >> 16);
    const float r = x - __uint_as_float(u & 0xFFFF0000u);
    l = (u16)(__float_as_uint(r) >> 16);
}
__device__ __forceinline__ void splitA4(float4 v, uint2& hi, uint2& lo) {
    u32 u0 = __float_as_uint(v.x), u1 = __float_as_uint(v.y),
        u2 = __float_as_uint(v.z), u3 = __float_as_uint(v.w);
    float r0 = v.x - __uint_as_float(u0 & 0xFFFF0000u);
    float r1 = v.y - __uint_as_float(u1 & 0xFFFF0000u);
    float r2 = v.z - __uint_as_float(u2 & 0xFFFF0000u);
    float r3 = v.w - __uint_as_float(u3 & 0xFFFF0000u);
    hi.x = pack_hi2(u0, u1);
    hi.y = pack_hi2(u2, u3);
    lo.x = pack_hi2(__float_as_uint(r0), __float_as_uint(r1));
    lo.y = pack_hi2(__float_as_uint(r2), __float_as_uint(r3));
}

// async global->LDS, 16 B per lane; lds base must be wave-uniform
__device__ __forceinline__ void gld16(const u16* g, u16* l) {
    __builtin_amdgcn_global_load_lds(
        (const __attribute__((address_space(1))) u32*)g,
        (__attribute__((address_space(3))) u32*)l, 16, 0, 0);
}

// ---------------------------------------------------------------------------
// Combined weight conversion (ONE launch): 13 z-slices ->
//  z=0 eh, z=1 dh, z=2 w1, z=3..10 heads h, z=11 enc, z=12 dec
// W fp32 [K][1024] -> hi/lo planes, k-tiled transposed  Wt[kt][n][32].
// ---------------------------------------------------------------------------
struct WSplitArgs {
    const float* src[6];
    u16* hi[6];
    u16* lo[6];
};

__global__ __launch_bounds__(256) void split_weight_all(WSplitArgs args)
{
    const int z = blockIdx.z;
    int which, zz = 0;
    if (z < 3)       { which = z; }
    else if (z < 11) { which = 3; zz = z - 3; }
    else             { which = z - 7; }          // 4 = enc, 5 = dec
    const int KT = (which == 4) ? 17 : (which == 5 ? 3 : 32);
    const int kt = blockIdx.x;
    if (kt >= KT) return;
    const int K = KT * 32;
    const long long zoff = (long long)zz * K * 1024;
    const float* W  = args.src[which] + zoff;
    u16* hi = args.hi[which] + zoff;
    u16* lo = args.lo[which] + zoff;

    const int n0  = blockIdx.y * 128;
    const int tid = threadIdx.x;
    const int k   = tid >> 3;            // 0..31
    const int ng  = (tid & 7) * 16;      // 0,16,...,112
    const float* src = W + (long long)(kt * 32 + k) * 1024 + n0 + ng;
    u16* dh = hi + ((long long)kt * 1024 + n0) * 32 + k;
    u16* dl = lo + ((long long)kt * 1024 + n0) * 32 + k;
#pragma unroll
    for (int t = 0; t < 4; t++) {
        const float4 v = *(const float4*)(src + t * 4);
        u16 h0, l0, h1, l1, h2, l2, h3, l3;
        split1(v.x, h0, l0); split1(v.y, h1, l1);
        split1(v.z, h2, l2); split1(v.w, h3, l3);
        const int nb = (ng + t * 4) * 32;
        dh[nb]      = h0; dl[nb]      = l0;
        dh[nb + 32] = h1; dl[nb + 32] = l1;
        dh[nb + 64] = h2; dl[nb + 64] = l2;
        dh[nb + 96] = h3; dl[nb + 96] = l3;
    }
}

// ---------------------------------------------------------------------------
// Hybrid 16x16x32 geometry.
// Hi planes: staged via gld16 with conflict-free swizzle — logical k-group g
// of row r lives at LDS slot g ^ ((r>>1)&3) (each 8-lane b128 phase then
// covers all 32 banks).  Lo planes: direct global->VGPR (natural layout),
// waited on by the barrier's vmcnt drain alongside the gld16s.
// ---------------------------------------------------------------------------
#define HYB_GEOM \
    const int tid  = threadIdx.x; \
    const int lane = tid & 63; \
    const int wv   = tid >> 6; \
    const int wm   = wv >> 1, wn = wv & 1; \
    const int fr   = lane & 15; \
    const int fq   = lane >> 4; \
    const int m0   = blockIdx.y * 128; \
    const int n0   = blockIdx.x * 128; \
    const int lro2 = (lane >> 2) * 32 + (((lane & 3) ^ ((lane >> 3) & 3)) * 8); \
    const int br0  = wv * 16; \
    const int br1  = 64 + wv * 16; \
    const int fqx2 = (fq ^ ((fr >> 1) & 3)) * 8;

#define STAGE_HI(Ahp_, Bhp_, aoff_, boff_) \
    { \
        const u16* Ag_ = (Ahp_) + (aoff_); \
        const u16* Bg_ = (Bhp_) + (boff_); \
        gld16(Ag_ + br0 * 32 + lro2, &Ah[br0 * 32]); \
        gld16(Ag_ + br1 * 32 + lro2, &Ah[br1 * 32]); \
        gld16(Bg_ + br0 * 32 + lro2, &Bh[br0 * 32]); \
        gld16(Bg_ + br1 * 32 + lro2, &Bh[br1 * 32]); \
    }

#define LOAD_LO(Alp_, Blp_, aoff_, boff_, al_, bl_) \
    { \
        const u16* Al_ = (Alp_) + (aoff_); \
        const u16* Bl_ = (Blp_) + (boff_); \
        _Pragma("unroll") \
        for (int i = 0; i < 4; i++) { \
            al_[i] = *(const bf16x8*)(Al_ + (wm * 64 + i * 16 + fr) * 32 + fq * 8); \
            bl_[i] = *(const bf16x8*)(Bl_ + (wn * 64 + i * 16 + fr) * 32 + fq * 8); \
        } \
    }

#define MFMA_SLAB16(acc_, al_, bl_) \
    { \
        bf16x8 ah[4], bh[4]; \
        _Pragma("unroll") \
        for (int i = 0; i < 4; i++) { \
            ah[i] = *(const bf16x8*)&Ah[(wm * 64 + i * 16 + fr) * 32 + fqx2]; \
            bh[i] = *(const bf16x8*)&Bh[(wn * 64 + i * 16 + fr) * 32 + fqx2]; \
        } \
        _Pragma("unroll") \
        for (int i = 0; i < 4; i++) \
            _Pragma("unroll") \
            for (int j = 0; j < 4; j++) { \
                acc_[i][j] = __builtin_amdgcn_mfma_f32_16x16x32_bf16(ah[i], bh[j], acc_[i][j], 0, 0, 0); \
                acc_[i][j] = __builtin_amdgcn_mfma_f32_16x16x32_bf16(ah[i], bl_[j], acc_[i][j], 0, 0, 0); \
                acc_[i][j] = __builtin_amdgcn_mfma_f32_16x16x32_bf16(al_[i], bh[j], acc_[i][j], 0, 0, 0); \
            } \
    }

// ===========================================================================
// GEMM (fast path): hybrid staging.  OUTP=1: write hi/lo planes.
// OUTP=0: fp32 row-major [*, 1024].
// ===========================================================================
template <int RELU, int OUTP>
__global__ __launch_bounds__(256) void gemm_fast(
    const u16* __restrict__ Ahp, const u16* __restrict__ Alp, int MA, int moff,
    const u16* __restrict__ Bhp, const u16* __restrict__ Blp,
    const float* __restrict__ bias,
    float* __restrict__ Cf,
    u16* __restrict__ Chp, u16* __restrict__ Clp, int MC,
    int K)
{
    __shared__ alignas(16) u16 Ah[4096], Bh[4096];
    HYB_GEOM

    f32x4 acc[4][4];
#pragma unroll
    for (int i = 0; i < 4; i++)
#pragma unroll
        for (int j = 0; j < 4; j++) acc[i][j] = 0;

    const int KT = K >> 5;
    for (int kt = 0; kt < KT; kt++) {
        const long long aoff = ((long long)kt * MA + moff + m0) * 32;
        const long long boff = ((long long)kt * 1024 + n0) * 32;
        STAGE_HI(Ahp, Bhp, aoff, boff);
        bf16x8 al[4], bl[4];
        LOAD_LO(Alp, Blp, aoff, boff, al, bl);
        __syncthreads();
        MFMA_SLAB16(acc, al, bl);
        __syncthreads();
    }

#pragma unroll
    for (int j = 0; j < 4; j++) {
        const int n = n0 + wn * 64 + j * 16 + fr;
        const float bb = bias[n];
#pragma unroll
        for (int i = 0; i < 4; i++) {
#pragma unroll
            for (int r = 0; r < 4; r++) {
                const int m = m0 + wm * 64 + i * 16 + fq * 4 + r;
                float v = acc[i][j][r] + bb;
                if (RELU) v = fmaxf(v, 0.0f);
                if (OUTP) {
                    u16 h, l;
                    split1(v, h, l);
                    const long long d = ((long long)(n >> 5) * MC + moff + m) * 32 + (n & 31);
                    Chp[d] = h;
                    Clp[d] = l;
                } else {
                    Cf[(long long)m * 1024 + n] = v;
                }
            }
        }
    }
}

// ===========================================================================
// GEMM (convert path, enc/dec): A fp32 (2-region concat), split in-kernel
// via LDS; B async from planes (r5 structure).  Output: hi/lo planes.
// ===========================================================================
template <int RELU>
__global__ __launch_bounds__(256) void gemm_cvt(
    const float* __restrict__ src1, int lda1, int kofs1,
    const float* __restrict__ src2, int lda2, int ksplit,
    const u16* __restrict__ Bhp, const u16* __restrict__ Blp,
    const float* __restrict__ bias,
    u16* __restrict__ Chp, u16* __restrict__ Clp, int MC,
    int K)
{
    __shared__ alignas(16) u16 Ah[4096], Al[4096], Bh[4096], Bl[4096];
    const int tid  = threadIdx.x;
    const int lane = tid & 63;
    const int wv   = tid >> 6;
    const int wm   = wv >> 1, wn = wv & 1;
    const int fr   = lane & 15;
    const int fq   = lane >> 4;
    const int m0   = blockIdx.y * 128;
    const int n0   = blockIdx.x * 128;
    const int fqx  = (fq ^ (fr & 3)) * 8;
    const int lro  = (lane >> 2) * 32 + (((lane & 3) ^ ((lane >> 2) & 3)) * 8);
    const int br0  = wv * 16;
    const int br1  = 64 + wv * 16;
    const int ar   = tid >> 3;           // 0..31
    const int akq  = tid & 7;            // float4 group 0..7
    const int awoff = (((akq >> 1) ^ (ar & 3)) * 8) + (akq & 1) * 4;

    f32x4 acc[4][4];
#pragma unroll
    for (int i = 0; i < 4; i++)
#pragma unroll
        for (int j = 0; j < 4; j++) acc[i][j] = 0;

    const int KT = K >> 5;
    for (int kt = 0; kt < KT; kt++) {
        const int k0 = kt * 32;
        const float* srcp; int ldk, kc;
        if (k0 < ksplit) { srcp = src1; ldk = lda1; kc = k0 + kofs1; }
        else             { srcp = src2; ldk = lda2; kc = k0 - ksplit; }

        const u16* Bg  = Bhp + ((long long)kt * 1024 + n0) * 32;
        const u16* Bg2 = Blp + ((long long)kt * 1024 + n0) * 32;
        gld16(Bg  + br0 * 32 + lro, &Bh[br0 * 32]);
        gld16(Bg  + br1 * 32 + lro, &Bh[br1 * 32]);
        gld16(Bg2 + br0 * 32 + lro, &Bl[br0 * 32]);
        gld16(Bg2 + br1 * 32 + lro, &Bl[br1 * 32]);

#pragma unroll
        for (int it = 0; it < 4; it++) {
            const int row = ar + it * 32;
            const float4 v = *(const float4*)(srcp + (long long)(m0 + row) * ldk + kc + akq * 4);
            uint2 hi, lo;
            splitA4(v, hi, lo);
            *(uint2*)&Ah[row * 32 + awoff] = hi;
            *(uint2*)&Al[row * 32 + awoff] = lo;
        }
        __syncthreads();

        bf16x8 ah[4], al[4], bh[4], bl[4];
#pragma unroll
        for (int i = 0; i < 4; i++) {
            const int off = (wm * 64 + i * 16 + fr) * 32 + fqx;
            ah[i] = *(const bf16x8*)&Ah[off];
            al[i] = *(const bf16x8*)&Al[off];
        }
#pragma unroll
        for (int j = 0; j < 4; j++) {
            const int off = (wn * 64 + j * 16 + fr) * 32 + fqx;
            bh[j] = *(const bf16x8*)&Bh[off];
            bl[j] = *(const bf16x8*)&Bl[off];
        }
#pragma unroll
        for (int i = 0; i < 4; i++)
#pragma unroll
            for (int j = 0; j < 4; j++) {
                acc[i][j] = __builtin_amdgcn_mfma_f32_16x16x32_bf16(ah[i], bh[j], acc[i][j], 0, 0, 0);
                acc[i][j] = __builtin_amdgcn_mfma_f32_16x16x32_bf16(ah[i], bl[j], acc[i][j], 0, 0, 0);
                acc[i][j] = __builtin_amdgcn_mfma_f32_16x16x32_bf16(al[i], bh[j], acc[i][j], 0, 0, 0);
            }
        __syncthreads();
    }

#pragma unroll
    for (int j = 0; j < 4; j++) {
        const int n = n0 + wn * 64 + j * 16 + fr;
        const float bb = bias[n];
#pragma unroll
        for (int i = 0; i < 4; i++) {
#pragma unroll
            for (int r = 0; r < 4; r++) {
                const int m = m0 + wm * 64 + i * 16 + fq * 4 + r;
                float v = acc[i][j][r] + bb;
                if (RELU) v = fmaxf(v, 0.0f);
                u16 h, l;
                split1(v, h, l);
                const long long d = ((long long)(n >> 5) * MC + m) * 32 + (n & 31);
                Chp[d] = h;
                Clp[d] = l;
            }
        }
    }
}

// ===========================================================================
// Heads: per-head hybrid GEMM; epilogue writes relu(head) fp16 + partial
// score dots vs decH.  Grid (8, BC/128, 8).
// ===========================================================================
__global__ __launch_bounds__(256) void heads_kernel(
    const u16* __restrict__ Ahp, const u16* __restrict__ Alp, int MA, int moff,
    const u16* __restrict__ Whp, const u16* __restrict__ Wlp,
    const float* __restrict__ b_heads,
    const float* __restrict__ decH,      // chunk-local [BC][1024]
    __half* __restrict__ headsb,         // [BC][8][1024]
    float* __restrict__ scoresp)         // [64][BC]
{
    __shared__ alignas(16) u16 Ah[4096], Bh[4096];
    __shared__ float scred[2][128];
    HYB_GEOM
    const int h = blockIdx.z;
    const u16* Bhp = Whp + (long long)h * 1048576;
    const u16* Blp = Wlp + (long long)h * 1048576;
    const float* bias = b_heads + h * 1024;

    f32x4 acc[4][4];
#pragma unroll
    for (int i = 0; i < 4; i++)
#pragma unroll
        for (int j = 0; j < 4; j++) acc[i][j] = 0;

    for (int kt = 0; kt < 32; kt++) {
        const long long aoff = ((long long)kt * MA + moff + m0) * 32;
        const long long boff = ((long long)kt * 1024 + n0) * 32;
        STAGE_HI(Ahp, Bhp, aoff, boff);
        bf16x8 al[4], bl[4];
        LOAD_LO(Alp, Blp, aoff, boff, al, bl);
        __syncthreads();
        MFMA_SLAB16(acc, al, bl);
        __syncthreads();
    }

    // epilogue: relu -> fp16 headsb, partial score vs decH
    float part[4][4];
#pragma unroll
    for (int i = 0; i < 4; i++)
#pragma unroll
        for (int r = 0; r < 4; r++) part[i][r] = 0.0f;

#pragma unroll
    for (int j = 0; j < 4; j++) {
        const int n = n0 + wn * 64 + j * 16 + fr;
        const float bb = bias[n];
#pragma unroll
        for (int i = 0; i < 4; i++) {
#pragma unroll
            for (int r = 0; r < 4; r++) {
                const int b_loc = m0 + wm * 64 + i * 16 + fq * 4 + r;
                const float v = fmaxf(acc[i][j][r] + bb, 0.0f);
                headsb[((long long)b_loc * HEADS + h) * 1024 + n] = __float2half(v);
                part[i][r] = fmaf(v, decH[(long long)b_loc * 1024 + n], part[i][r]);
            }
        }
    }
#pragma unroll
    for (int off = 1; off < 16; off <<= 1)
#pragma unroll
        for (int i = 0; i < 4; i++)
#pragma unroll
            for (int r = 0; r < 4; r++)
                part[i][r] += __shfl_xor(part[i][r], off, 64);

    if (fr == 0) {
#pragma unroll
        for (int i = 0; i < 4; i++)
#pragma unroll
            for (int r = 0; r < 4; r++)
                scred[wn][wm * 64 + i * 16 + fq * 4 + r] = part[i][r];
    }
    __syncthreads();
    if (tid < 128) {
        const float sv = scred[0][tid] + scred[1][tid];
        scoresp[(long long)(h * 8 + blockIdx.x) * BC + m0 + tid] = sv;
    }
}

// ---------------------------------------------------------------------------
// context (+fused softmax): per row b, softmax over heads from scoresp,
// then ctx[b][d] = sum_h attn[h]*heads[b][h][d]; writes hi/lo planes.
// ---------------------------------------------------------------------------
__global__ __launch_bounds__(256) void context_kernel(
    const __half* __restrict__ headsb, const float* __restrict__ scoresp,
    u16* __restrict__ ctx_hi, u16* __restrict__ ctx_lo, int MC, int row0)
{
    __shared__ float sc_s[64];
    __shared__ float attn_s[HEADS];
    const int b = blockIdx.x;
    const int tid = threadIdx.x;
    if (tid < 64) sc_s[tid] = scoresp[(long long)tid * BC + b];
    __syncthreads();
    if (tid == 0) {
        float sc[HEADS];
#pragma unroll
        for (int h = 0; h < HEADS; h++) {
            float s = 0.0f;
#pragma unroll
            for (int nt = 0; nt < 8; nt++) s += sc_s[h * 8 + nt];
            sc[h] = s;
        }
        float mx = sc[0];
#pragma unroll
        for (int h = 1; h < HEADS; h++) mx = fmaxf(mx, sc[h]);
        float e[HEADS], sum = 0.0f;
#pragma unroll
        for (int h = 0; h < HEADS; h++) { e[h] = __expf(sc[h] - mx); sum += e[h]; }
        const float inv = 1.0f / sum;
#pragma unroll
        for (int h = 0; h < HEADS; h++) attn_s[h] = e[h] * inv;
    }
    __syncthreads();

    const int d = tid * 4;
    float w[HEADS];
#pragma unroll
    for (int h = 0; h < HEADS; h++) w[h] = attn_s[h];
    float4 acc = make_float4(0.f, 0.f, 0.f, 0.f);
#pragma unroll
    for (int h = 0; h < HEADS; h++) {
        const __half2* hp = (const __half2*)(headsb + ((long long)b * HEADS + h) * 1024 + d);
        const float2 f0 = __half22float2(hp[0]);
        const float2 f1 = __half22float2(hp[1]);
        acc.x = fmaf(w[h], f0.x, acc.x);
        acc.y = fmaf(w[h], f0.y, acc.y);
        acc.z = fmaf(w[h], f1.x, acc.z);
        acc.w = fmaf(w[h], f1.y, acc.w);
    }
    uint2 hi, lo;
    splitA4(acc, hi, lo);
    const long long off = ((long long)(d >> 5) * MC + row0 + b) * 32 + (d & 31);
    *(uint2*)(ctx_hi + off) = hi;
    *(uint2*)(ctx_lo + off) = lo;
}

// ---------------------------------------------------------------------------
// fc2: q[b] = sum_d x[b,d]*W2[d] + b2[0]
// ---------------------------------------------------------------------------
__global__ __launch_bounds__(256) void fc2_kernel(
    const float* __restrict__ x, const float* __restrict__ W2,
    const float* __restrict__ b2, float* __restrict__ q)
{
    const int b   = blockIdx.x;
    const int tid = threadIdx.x;
    __shared__ float red[4];

    const float4 xv = *(const float4*)(x + (long long)b * 1024 + tid * 4);
    const float4 wv = *(const float4*)(W2 + tid * 4);
    float p = xv.x * wv.x + xv.y * wv.y + xv.z * wv.z + xv.w * wv.w;
#pragma unroll
    for (int off = 32; off > 0; off >>= 1) p += __shfl_down(p, off, 64);
    if ((tid & 63) == 0) red[tid >> 6] = p;
    __syncthreads();
    if (tid == 0) q[b] = red[0] + red[1] + red[2] + red[3] + b2[0];
}

// ---------------------------------------------------------------------------
extern "C" void kernel_launch(void* const* d_in, const int* in_sizes, int n_in,
                              void* d_out, int out_size, void* d_ws, size_t ws_size,
                              hipStream_t stream)
{
    const float* s        = (const float*)d_in[0];
    const float* a        = (const float*)d_in[1];
    const float* W_enc_in = (const float*)d_in[2];
    const float* b_enc_in = (const float*)d_in[3];
    const float* W_dec_in = (const float*)d_in[4];
    const float* b_dec_in = (const float*)d_in[5];
    const float* W_eh     = (const float*)d_in[6];
    const float* b_eh     = (const float*)d_in[7];
    const float* W_heads  = (const float*)d_in[8];
    const float* b_heads  = (const float*)d_in[9];
    const float* W_dh     = (const float*)d_in[10];
    const float* b_dh     = (const float*)d_in[11];
    const float* W1       = (const float*)d_in[12];
    const float* b1       = (const float*)d_in[13];
    const float* W2       = (const float*)d_in[14];
    const float* b2       = (const float*)d_in[15];
    float* q_out = (float*)d_out;

    // ---- weight plane layout (shorts) -------------------------------------
    u16* P = (u16*)d_ws;
    u16* enc_hi = P; P += 557056;      // 544*1024
    u16* enc_lo = P; P += 557056;
    u16* dec_hi = P; P += 98304;       // 96*1024
    u16* dec_lo = P; P += 98304;
    u16* eh_hi  = P; P += 1048576;
    u16* eh_lo  = P; P += 1048576;
    u16* dh_hi  = P; P += 1048576;
    u16* dh_lo  = P; P += 1048576;
    u16* w1_hi  = P; P += 1048576;
    u16* w1_lo  = P; P += 1048576;
    u16* wh_hi  = P; P += 8388608;     // 8*1024*1024
    u16* wh_lo  = P; P += 8388608;
    char* act = (char*)P;              // 48,758,784 bytes consumed

    const dim3 blk(256);

    // ---- weight conversions: ONE launch -----------------------------------
    WSplitArgs wa;
    wa.src[0] = W_eh;    wa.hi[0] = eh_hi;  wa.lo[0] = eh_lo;
    wa.src[1] = W_dh;    wa.hi[1] = dh_hi;  wa.lo[1] = dh_lo;
    wa.src[2] = W1;      wa.hi[2] = w1_hi;  wa.lo[2] = w1_lo;
    wa.src[3] = W_heads; wa.hi[3] = wh_hi;  wa.lo[3] = wh_lo;
    wa.src[4] = W_enc_in; wa.hi[4] = enc_hi; wa.lo[4] = enc_lo;
    wa.src[5] = W_dec_in; wa.hi[5] = dec_hi; wa.lo[5] = dec_lo;
    split_weight_all<<<dim3(32, 8, 13), blk, 0, stream>>>(wa);

    const bool high = (ws_size >= 150011904ULL);

    if (high) {
        u16*    bufA_hi = (u16*)act;
        u16*    bufA_lo = bufA_hi + 8388608;
        __half* headsb  = (__half*)act;
        u16*    encH_hi = (u16*)(act + 33554432);
        u16*    encH_lo = encH_hi + 8388608;
        float*  decH    = (float*)(act + 2LL * 33554432);
        float*  scoresp = (float*)(act + 3LL * 33554432);

        const dim3 gg(8, 64, 1);
        gemm_cvt<0><<<gg, blk, 0, stream>>>(s, 512, 0, a, 128, 512,
            enc_hi, enc_lo, b_enc_in, bufA_hi, bufA_lo, 8192, 544);
        gemm_fast<1, 1><<<gg, blk, 0, stream>>>(bufA_hi, bufA_lo, 8192, 0,
            eh_hi, eh_lo, b_eh, nullptr, encH_hi, encH_lo, 8192, 1024);
        gemm_cvt<0><<<gg, blk, 0, stream>>>(a, 128, 32, a, 128, 1 << 28,
            dec_hi, dec_lo, b_dec_in, bufA_hi, bufA_lo, 8192, 96);
        gemm_fast<1, 0><<<gg, blk, 0, stream>>>(bufA_hi, bufA_lo, 8192, 0,
            dh_hi, dh_lo, b_dh, decH, nullptr, nullptr, 0, 1024);

        for (int c = 0; c < BATCH / BC; c++) {
            heads_kernel<<<dim3(8, BC / 128, 8), blk, 0, stream>>>(
                encH_hi, encH_lo, 8192, c * BC, wh_hi, wh_lo, b_heads,
                decH + (long long)c * BC * 1024, headsb, scoresp);
            context_kernel<<<dim3(BC), blk, 0, stream>>>(
                headsb, scoresp, encH_hi, encH_lo, 8192, c * BC);
        }
        gemm_fast<1, 0><<<gg, blk, 0, stream>>>(encH_hi, encH_lo, 8192, 0,
            w1_hi, w1_lo, b1, decH, nullptr, nullptr, 0, 1024);
        fc2_kernel<<<dim3(BATCH), blk, 0, stream>>>(decH, W2, b2, q_out);
    } else {
        __half* headsb  = (__half*)act;
        u16*    bufA_hi = (u16*)act;
        u16*    bufA_lo = bufA_hi + 2097152;
        u16*    encH_hi = (u16*)(act + 33554432);
        u16*    encH_lo = encH_hi + 2097152;
        float*  decH    = (float*)(act + 33554432 + 8388608);
        float*  scoresp = (float*)(act + 33554432 + 2LL * 8388608);

        const dim3 gg(8, BC / 128, 1);
        for (int c = 0; c < BATCH / BC; c++) {
            const float* sC = s + (long long)c * BC * 512;
            const float* aC = a + (long long)c * BC * 128;
            gemm_cvt<0><<<gg, blk, 0, stream>>>(sC, 512, 0, aC, 128, 512,
                enc_hi, enc_lo, b_enc_in, bufA_hi, bufA_lo, BC, 544);
            gemm_fast<1, 1><<<gg, blk, 0, stream>>>(bufA_hi, bufA_lo, BC, 0,
                eh_hi, eh_lo, b_eh, nullptr, encH_hi, encH_lo, BC, 1024);
            gemm_cvt<0><<<gg, blk, 0, stream>>>(aC, 128, 32, aC, 128, 1 << 28,
                dec_hi, dec_lo, b_dec_in, bufA_hi, bufA_lo, BC, 96);
            gemm_fast<1, 0><<<gg, blk, 0, stream>>>(bufA_hi, bufA_lo, BC, 0,
                dh_hi, dh_lo, b_dh, decH, nullptr, nullptr, 0, 1024);
            heads_kernel<<<dim3(8, BC / 128, 8), blk, 0, stream>>>(
                encH_hi, encH_lo, BC, 0, wh_hi, wh_lo, b_heads,
                decH, headsb, scoresp);
            context_kernel<<<dim3(BC), blk, 0, stream>>>(
                headsb, scoresp, encH_hi, encH_lo, BC, 0);
            gemm_fast<1, 0><<<gg, blk, 0, stream>>>(encH_hi, encH_lo, BC, 0,
                w1_hi, w1_lo, b1, decH, nullptr, nullptr, 0, 1024);
            fc2_kernel<<<dim3(BC), blk, 0, stream>>>(decH, W2, b2, q_out + (long long)c * BC);
        }
    }
}